// Round 11
// baseline (96.172 us; speedup 1.0000x reference)
//
#include <hip/hip_runtime.h>
#include <hip/hip_bf16.h>

typedef __attribute__((ext_vector_type(4)))  float f32x4;
typedef __attribute__((ext_vector_type(16))) float f32x16;
typedef __attribute__((ext_vector_type(8)))  short bf16x8;
typedef __attribute__((ext_vector_type(4)))  unsigned u32x4;
typedef __attribute__((ext_vector_type(2)))  unsigned u32x2;

#define NEG_INF_F (-1000000000.0f)

__device__ inline unsigned pkbf(float a, float b) {
    union { __hip_bfloat16 h; unsigned short u; } x, y;
    x.h = __float2bfloat16(a);
    y.h = __float2bfloat16(b);
    return (unsigned)x.u | ((unsigned)y.u << 16);
}
__device__ inline short bf1(float a) {
    union { __hip_bfloat16 h; short s; } x; x.h = __float2bfloat16(a); return x.s;
}

// ---------- preprocess: K -> bf16 row-major, V2 -> bf16 transposed, mask -> f32 ----------
// grid (64 bh, 16 chunk), 256 thr. Each block: 64 keys x 64 d.
__global__ __launch_bounds__(256) void aoa_prep_kernel(
    const float* __restrict__ keyp, const float* __restrict__ v2,
    const int* __restrict__ maskp,
    short* __restrict__ Kb, short* __restrict__ Vt, float* __restrict__ maskw)
{
    const int bh  = blockIdx.x;
    const int c   = blockIdx.y;
    const int tid = threadIdx.x;
    const int kv0 = c * 64;
    const size_t base = (size_t)bh * 65536;

    __shared__ short T[64][72];

    // K convert (coalesced both sides) + V2 -> LDS
    {
        const int k    = tid >> 2;          // 0..63
        const int dseg = (tid & 3) << 4;    // 0,16,32,48
        const f32x4* ks = (const f32x4*)(keyp + base + (size_t)(kv0 + k) * 64 + dseg);
        f32x4 a0 = ks[0], a1 = ks[1], a2 = ks[2], a3 = ks[3];
        u32x4 w0 = (u32x4){pkbf(a0[0],a0[1]), pkbf(a0[2],a0[3]), pkbf(a1[0],a1[1]), pkbf(a1[2],a1[3])};
        u32x4 w1 = (u32x4){pkbf(a2[0],a2[1]), pkbf(a2[2],a2[3]), pkbf(a3[0],a3[1]), pkbf(a3[2],a3[3])};
        short* kd = Kb + base + (size_t)(kv0 + k) * 64 + dseg;
        *(u32x4*)kd = w0; *(u32x4*)(kd + 8) = w1;

        const f32x4* vs = (const f32x4*)(v2 + base + (size_t)(kv0 + k) * 64 + dseg);
        f32x4 b0 = vs[0], b1 = vs[1], b2 = vs[2], b3 = vs[3];
        u32x4 t0 = (u32x4){pkbf(b0[0],b0[1]), pkbf(b0[2],b0[3]), pkbf(b1[0],b1[1]), pkbf(b1[2],b1[3])};
        u32x4 t1 = (u32x4){pkbf(b2[0],b2[1]), pkbf(b2[2],b2[3]), pkbf(b3[0],b3[1]), pkbf(b3[2],b3[3])};
        *(u32x4*)&T[k][dseg]     = t0;
        *(u32x4*)&T[k][dseg + 8] = t1;
    }
    __syncthreads();
    // Vt write: d = tid>>2, 16 keys per thread
    {
        const int d    = tid >> 2;
        const int kseg = (tid & 3) << 4;
        short tmp[16];
        #pragma unroll
        for (int i = 0; i < 16; ++i) tmp[i] = T[kseg + i][d];
        short* vd = Vt + base + (size_t)d * 1024 + kv0 + kseg;
        *(u32x4*)vd       = *(u32x4*)&tmp[0];
        *(u32x4*)(vd + 8) = *(u32x4*)&tmp[8];
    }
    // mask (8 b's; blocks bh<8, c==0)
    if (c == 0 && bh < 8) {
        #pragma unroll
        for (int i = 0; i < 4; ++i) {
            int idx = tid * 4 + i - 3 * tid;   // avoid fancy: recompute below
        }
        for (int i = tid; i < 1024; i += 256)
            maskw[bh * 1024 + i] = maskp[bh * 1024 + i] ? 0.0f : NEG_INF_F;
    }
}

// ---------- attention: barrier-free, LDS-free hot loop ----------
// grid (64 bh, 8 qt), 256 thr = 4 warps x 32 q. All operands direct from
// preprocessed bf16 global (L2/XCD-local). mfma_f32_32x32x16_bf16:
//   A[m][k]: m=lane&31, k=(lane>>5)*8+j ; B[k][n]: n=lane&31, k=(lane>>5)*8+j
//   C[m][n]: n=lane&31, m=crow(r,h)=(r&3)+8*(r>>2)+4*(lane>>5)
__global__ __launch_bounds__(256) void aoa_attn_kernel(
    const float* __restrict__ gv,
    const float* __restrict__ q2,
    const float* __restrict__ keyp,
    const float* __restrict__ v1,
    const float* __restrict__ W,
    const float* __restrict__ bch,
    const short* __restrict__ Kb,
    const short* __restrict__ Vt,
    const float* __restrict__ maskw,
    float* __restrict__ out)
{
    constexpr int S = 1024, D = 64;
    const int bh  = blockIdx.x;
    const int qt  = blockIdx.y;
    const int b   = bh >> 3;
    const int tid = threadIdx.x;
    const int lane = tid & 63;
    const int wid = tid >> 6;
    const int l31 = lane & 31;
    const int h   = lane >> 5;

    float* out_attn = out + 512;
    if (bh == 0 && qt == 0) { out[tid] = gv[tid]; out[tid + 256] = gv[tid + 256]; }

    const size_t base  = (size_t)bh * S * D;
    const size_t bbase = (size_t)bh * 65536;
    const float* Qp  = q2 + base;
    const float* V1p = v1 + base;
    const float* Kp  = keyp + base;
    const float* mrow = maskw + b * S;

    const int q0   = qt * 128 + wid * 32;
    const int qrow = q0 + l31;

    // Q B-fragments
    bf16x8 bq[4];
    #pragma unroll
    for (int ds = 0; ds < 4; ++ds) {
        const f32x4* p = (const f32x4*)(Qp + (size_t)qrow * D + ds * 16 + h * 8);
        f32x4 x0 = p[0], x1 = p[1];
        u32x4 u = (u32x4){pkbf(x0[0], x0[1]), pkbf(x0[2], x0[3]),
                          pkbf(x1[0], x1[1]), pkbf(x1[2], x1[3])};
        bq[ds] = *(bf16x8*)&u;
    }

    f32x16 acc_o[2];
    #pragma unroll
    for (int dh = 0; dh < 2; ++dh)
        #pragma unroll
        for (int r = 0; r < 16; ++r) acc_o[dh][r] = 0.0f;

    float m_run = -1e30f, l_run = 0.0f;
    const float SC = 0.125f * 1.4426950408889634f;

    const short* Kbase  = Kb + bbase + (size_t)l31 * 64 + h * 8;     // + key*64
    const short* Vbase  = Vt + bbase + (size_t)l31 * 1024 + h * 8;   // + d*1024 + key

    #pragma unroll 2
    for (int t = 0; t < 16; ++t) {
        const int kt = t * 64;

        // ---- QK^T half 0/1 (A-frags direct from global bf16) ----
        f32x16 a0, a1;
        #pragma unroll
        for (int r = 0; r < 16; ++r) { a0[r] = 0.0f; a1[r] = 0.0f; }
        #pragma unroll
        for (int ds = 0; ds < 4; ++ds) {
            bf16x8 ak = *(const bf16x8*)(Kbase + (size_t)kt * 64 + ds * 16);
            a0 = __builtin_amdgcn_mfma_f32_32x32x16_bf16(ak, bq[ds], a0, 0, 0, 0);
        }
        #pragma unroll
        for (int ds = 0; ds < 4; ++ds) {
            bf16x8 ak = *(const bf16x8*)(Kbase + (size_t)(kt + 32) * 64 + ds * 16);
            a1 = __builtin_amdgcn_mfma_f32_32x32x16_bf16(ak, bq[ds], a1, 0, 0, 0);
        }

        // ---- softmax half 0 ----
        unsigned w0[8];
        {
            float s[16], tmax = -1e30f;
            #pragma unroll
            for (int g = 0; g < 4; ++g) {
                f32x4 mk = *(const f32x4*)&mrow[kt + g * 8 + h * 4];
                #pragma unroll
                for (int j = 0; j < 4; ++j) {
                    float val = fmaf(a0[g * 4 + j], SC, mk[j]);
                    s[g * 4 + j] = val;
                    tmax = fmaxf(tmax, val);
                }
            }
            tmax = fmaxf(tmax, __shfl_xor(tmax, 32));
            if (__any(tmax > m_run + 8.0f)) {
                float mnew = fmaxf(m_run, tmax);
                float r = __builtin_amdgcn_exp2f(m_run - mnew);
                l_run *= r;
                #pragma unroll
                for (int dh = 0; dh < 2; ++dh)
                    #pragma unroll
                    for (int r2 = 0; r2 < 16; ++r2) acc_o[dh][r2] *= r;
                m_run = mnew;
            }
            float ps0 = 0.f, ps1 = 0.f;
            #pragma unroll
            for (int i = 0; i < 8; ++i) {
                float p0 = __builtin_amdgcn_exp2f(s[2 * i]     - m_run);
                float p1 = __builtin_amdgcn_exp2f(s[2 * i + 1] - m_run);
                ps0 += p0; ps1 += p1;
                w0[i] = pkbf(p0, p1);
            }
            float psum = ps0 + ps1;
            psum += __shfl_xor(psum, 32);
            l_run += psum;
        }

        // ---- PV half 0 ----
        #pragma unroll
        for (int t2 = 0; t2 < 2; ++t2) {
            u32x2 r0 = __builtin_amdgcn_permlane32_swap(w0[t2 * 4 + 0], w0[t2 * 4 + 2], false, false);
            u32x2 r1 = __builtin_amdgcn_permlane32_swap(w0[t2 * 4 + 1], w0[t2 * 4 + 3], false, false);
            u32x4 ua = (u32x4){r0[0], r1[0], r0[1], r1[1]};
            bf16x8 pa = *(bf16x8*)&ua;
            #pragma unroll
            for (int dh = 0; dh < 2; ++dh) {
                bf16x8 bv = *(const bf16x8*)(Vbase + (size_t)(dh * 32) * 1024 + kt + t2 * 16);
                acc_o[dh] = __builtin_amdgcn_mfma_f32_32x32x16_bf16(pa, bv, acc_o[dh], 0, 0, 0);
            }
        }

        // ---- softmax half 1 ----
        unsigned w1[8];
        {
            float s[16], tmax = -1e30f;
            #pragma unroll
            for (int g = 0; g < 4; ++g) {
                f32x4 mk = *(const f32x4*)&mrow[kt + 32 + g * 8 + h * 4];
                #pragma unroll
                for (int j = 0; j < 4; ++j) {
                    float val = fmaf(a1[g * 4 + j], SC, mk[j]);
                    s[g * 4 + j] = val;
                    tmax = fmaxf(tmax, val);
                }
            }
            tmax = fmaxf(tmax, __shfl_xor(tmax, 32));
            if (__any(tmax > m_run + 8.0f)) {
                float mnew = fmaxf(m_run, tmax);
                float r = __builtin_amdgcn_exp2f(m_run - mnew);
                l_run *= r;
                #pragma unroll
                for (int dh = 0; dh < 2; ++dh)
                    #pragma unroll
                    for (int r2 = 0; r2 < 16; ++r2) acc_o[dh][r2] *= r;
                m_run = mnew;
            }
            float ps0 = 0.f, ps1 = 0.f;
            #pragma unroll
            for (int i = 0; i < 8; ++i) {
                float p0 = __builtin_amdgcn_exp2f(s[2 * i]     - m_run);
                float p1 = __builtin_amdgcn_exp2f(s[2 * i + 1] - m_run);
                ps0 += p0; ps1 += p1;
                w1[i] = pkbf(p0, p1);
            }
            float psum = ps0 + ps1;
            psum += __shfl_xor(psum, 32);
            l_run += psum;
        }

        // ---- PV half 1 ----
        #pragma unroll
        for (int t2 = 0; t2 < 2; ++t2) {
            u32x2 r0 = __builtin_amdgcn_permlane32_swap(w1[t2 * 4 + 0], w1[t2 * 4 + 2], false, false);
            u32x2 r1 = __builtin_amdgcn_permlane32_swap(w1[t2 * 4 + 1], w1[t2 * 4 + 3], false, false);
            u32x4 ua = (u32x4){r0[0], r1[0], r0[1], r1[1]};
            bf16x8 pa = *(bf16x8*)&ua;
            #pragma unroll
            for (int dh = 0; dh < 2; ++dh) {
                bf16x8 bv = *(const bf16x8*)(Vbase + (size_t)(dh * 32) * 1024 + kt + 32 + t2 * 16);
                acc_o[dh] = __builtin_amdgcn_mfma_f32_32x32x16_bf16(pa, bv, acc_o[dh], 0, 0, 0);
            }
        }
    }

    // ---- channel gate ----
    f32x16 acc_g[2];
    #pragma unroll
    for (int eh = 0; eh < 2; ++eh)
        #pragma unroll
        for (int r = 0; r < 16; ++r) acc_g[eh][r] = 0.0f;

    bf16x8 bam[4];
    #pragma unroll
    for (int ds = 0; ds < 4; ++ds) {
        const f32x4* p1 = (const f32x4*)(V1p + (size_t)qrow * D + ds * 16 + h * 8);
        const f32x4* pk = (const f32x4*)(Kp  + (size_t)qrow * D + ds * 16 + h * 8);
        f32x4 a0 = p1[0], a1 = p1[1], c0 = pk[0], c1 = pk[1];
        u32x4 u = (u32x4){pkbf(a0[0]*c0[0], a0[1]*c0[1]), pkbf(a0[2]*c0[2], a0[3]*c0[3]),
                          pkbf(a1[0]*c1[0], a1[1]*c1[1]), pkbf(a1[2]*c1[2], a1[3]*c1[3])};
        bam[ds] = *(bf16x8*)&u;
    }
    #pragma unroll
    for (int eh = 0; eh < 2; ++eh) {
        #pragma unroll
        for (int ds = 0; ds < 4; ++ds) {
            const f32x4* pw = (const f32x4*)(W + (size_t)(eh * 32 + l31) * D + ds * 16 + h * 8);
            f32x4 x0 = pw[0], x1 = pw[1];
            u32x4 u = (u32x4){pkbf(x0[0], x0[1]), pkbf(x0[2], x0[3]),
                              pkbf(x1[0], x1[1]), pkbf(x1[2], x1[3])};
            bf16x8 bw = *(bf16x8*)&u;
            acc_g[eh] = __builtin_amdgcn_mfma_f32_32x32x16_bf16(bam[ds], bw, acc_g[eh], 0, 0, 0);
        }
    }

    // ---- epilogue: 1/l via shfl (distinct-reg safe), fused sigmoid ----
    float inv = 1.0f / l_run;
    const float bv0 = bch[l31], bv1 = bch[32 + l31];
    #pragma unroll
    for (int dh = 0; dh < 2; ++dh) {
        const float bc = dh ? bv1 : bv0;
        #pragma unroll
        for (int r = 0; r < 16; ++r) {
            const int ql = (r & 3) + 8 * (r >> 2) + 4 * h;   // crow(r,h)
            float invl = __shfl(inv, ql);
            float o = acc_o[dh][r] * invl;
            float z = acc_g[dh][r] + bc;
            float gate = 1.0f / (1.0f + __expf(-z));
            out_attn[base + (size_t)(q0 + ql) * D + dh * 32 + l31] = o * gate;
        }
    }
}

extern "C" void kernel_launch(void* const* d_in, const int* in_sizes, int n_in,
                              void* d_out, int out_size, void* d_ws, size_t ws_size,
                              hipStream_t stream) {
    const float* gv   = (const float*)d_in[0];
    const float* q2   = (const float*)d_in[1];
    const float* keyp = (const float*)d_in[2];
    const int*   mask = (const int*)  d_in[3];
    const float* v1   = (const float*)d_in[4];
    const float* v2   = (const float*)d_in[5];
    const float* W    = (const float*)d_in[6];
    const float* bch  = (const float*)d_in[7];
    float* out = (float*)d_out;

    short* Kb    = (short*)d_ws;                     // 64*1024*64 bf16 = 16.8 MB
    short* Vt    = Kb + 64ull * 1024 * 64;           // 16.8 MB
    float* maskw = (float*)(Vt + 64ull * 1024 * 64); // 32 KB  (total ~33.6 MB <= ws)

    dim3 pgrid(64, 16);
    aoa_prep_kernel<<<pgrid, 256, 0, stream>>>(keyp, v2, mask, Kb, Vt, maskw);

    dim3 agrid(64, 8);
    aoa_attn_kernel<<<agrid, 256, 0, stream>>>(gv, q2, keyp, v1, W, bch, Kb, Vt, maskw, out);
}

// Round 12
// 52.917 us; speedup vs baseline: 1.8174x; 1.8174x over previous
//
#include <hip/hip_runtime.h>
#include <hip/hip_bf16.h>

typedef __attribute__((ext_vector_type(4)))  float f32x4;
typedef __attribute__((ext_vector_type(8)))  short bf16x8;
typedef __attribute__((ext_vector_type(4)))  unsigned u32x4;
typedef __attribute__((ext_vector_type(2)))  unsigned u32x2;

#define NEG_INF_F (-1000000000.0f)

// native bf16 RNE converts -> compiler emits v_cvt_pk_bf16_f32
__device__ inline unsigned pkbf(float a, float b) {
    union { __hip_bfloat16 h; unsigned short u; } x, y;
    x.h = __float2bfloat16(a);
    y.h = __float2bfloat16(b);
    return (unsigned)x.u | ((unsigned)y.u << 16);
}

// R12: 16x16x32 geometry for 4 waves/SIMD. Block = 1024 thr = 16 warps x 16 q = 256 q.
// Grid (64 bh, 4 qt) = 256 blocks = 1/CU = 16 waves/CU = 4/SIMD (2x R8's TLP).
// Swapped QK: S^T[key][q] = A(K) x B(Q): A m=l15=key(kb*16+l15), k=l4*8+j=d ;
//   B n=l15=q, k=l4*8+j=d ; C col=l15=q, row=l4*4+r=key  (R2-verified layout).
// Softmax in-lane: 16 keys/lane for q=l15; reduce over l4 via 2x shfl_xor.
// PV O[q][d] = A(P) x B(V): A m=l15=q(SAME as softmax), k=key -> cross-l4 shuffle:
//   key=ks*32+l4*8+j held by srclane ((l4&1)<<5)+l15 (+16 for j>=4), slot 4ks+2*(l4>>1).
// K/Vt LDS: stride 64 shorts + XOR swizzle col^((row&7)<<3) -> aggregate conflict-free.
// Double-buffered, loads at top of iter, ds_write at tail (T14).
__global__ __launch_bounds__(1024, 4) void aoa_attn_kernel(
    const float* __restrict__ gv,
    const float* __restrict__ q2,
    const float* __restrict__ keyp,
    const int*   __restrict__ maskp,
    const float* __restrict__ v1,
    const float* __restrict__ v2,
    const float* __restrict__ W,
    const float* __restrict__ bch,
    float* __restrict__ out)
{
    constexpr int S = 1024, D = 64;
    const int bh  = blockIdx.x;
    const int qt  = blockIdx.y;
    const int b   = bh >> 3;
    const int tid = threadIdx.x;
    const int wid = tid >> 6;      // 0..15
    const int lane = tid & 63;
    const int l15 = lane & 15;
    const int l4  = lane >> 4;     // 0..3

    float* out_attn = out + 512;
    if (bh == 0 && qt == 0 && tid < 512) out[tid] = gv[tid];

    __shared__ float maskf[S];          // 0 or NEG_INF
    __shared__ short Kl[2][4096];       // [buf][key*64 + (d ^ ((key&7)<<3))]
    __shared__ short Vl[2][4096];       // [buf][d*64 + (key ^ ((d&7)<<3))]

    maskf[tid] = maskp[b * S + tid] ? 0.0f : NEG_INF_F;

    const size_t base = (size_t)bh * S * D;
    const float* Qp  = q2   + base;
    const float* Kp  = keyp + base;
    const float* V1p = v1   + base;
    const float* V2p = v2   + base;

    const int q0   = qt * 256 + wid * 16;
    const int qrow = q0 + l15;

    // Q B-fragments: bq[ds][j] = Q[qrow][ds*32 + l4*8 + j]
    bf16x8 bq[2];
    #pragma unroll
    for (int ds = 0; ds < 2; ++ds) {
        const f32x4* p = (const f32x4*)(Qp + (size_t)qrow * D + ds * 32 + l4 * 8);
        f32x4 x0 = p[0], x1 = p[1];
        u32x4 u = (u32x4){pkbf(x0[0], x0[1]), pkbf(x0[2], x0[3]),
                          pkbf(x1[0], x1[1]), pkbf(x1[2], x1[3])};
        bq[ds] = *(bf16x8*)&u;
    }

    f32x4 acc_o[4];
    #pragma unroll
    for (int i = 0; i < 4; ++i) acc_o[i] = (f32x4){0.f, 0.f, 0.f, 0.f};
    float m_run = -1e30f, l_run = 0.0f;
    const float SC = 0.125f * 1.4426950408889634f;   // D^-0.5 * log2(e)

    // staging indices (1024 threads): K 4 floats/thr, Vt 4 floats/thr
    const int sk  = tid >> 4;           // K row (key) 0..63
    const int sd0 = (tid & 15) << 2;    // K d-col 0..60
    const int vd  = tid & 63;           // Vt row (d)
    const int vk0 = (tid >> 6) << 2;    // Vt key0 0..60
    const int kwr = sk * 64 + (sd0 ^ ((sk & 7) << 3));
    const int vwr = vd * 64 + (vk0 ^ ((vd & 7) << 3));

    // prologue: tile 0 -> regs -> buf 0
    f32x4 kreg;
    float vv[4];
    kreg = *(const f32x4*)(Kp + (size_t)sk * D + sd0);
    #pragma unroll
    for (int i = 0; i < 4; ++i) vv[i] = V2p[(size_t)(vk0 + i) * D + vd];
    *(u32x2*)&Kl[0][kwr] = (u32x2){pkbf(kreg[0], kreg[1]), pkbf(kreg[2], kreg[3])};
    *(u32x2*)&Vl[0][vwr] = (u32x2){pkbf(vv[0], vv[1]), pkbf(vv[2], vv[3])};
    int cur = 0;

    const int srcA = ((l4 & 1) << 5) + l15;
    const int srcB = srcA + 16;
    const bool h2  = (l4 >> 1) != 0;

    for (int t = 0; t < 16; ++t) {
        const int kt = t * 64;
        __syncthreads();   // buf[cur] + maskf visible; buf[cur^1] free

        if (t < 15) {   // issue next tile's loads; land under compute
            kreg = *(const f32x4*)(Kp + (size_t)(kt + 64 + sk) * D + sd0);
            #pragma unroll
            for (int i = 0; i < 4; ++i) vv[i] = V2p[(size_t)(kt + 64 + vk0 + i) * D + vd];
        }

        // ---- QK^T: S^T[key][q], 4 kb-blocks of 16 keys ----
        f32x4 accs[4];
        #pragma unroll
        for (int kb = 0; kb < 4; ++kb) {
            f32x4 a = (f32x4){0.f, 0.f, 0.f, 0.f};
            #pragma unroll
            for (int ds = 0; ds < 2; ++ds) {
                const int row = kb * 16 + l15;
                bf16x8 ak = *(const bf16x8*)&Kl[cur][row * 64 + ((ds * 32 + l4 * 8) ^ ((row & 7) << 3))];
                a = __builtin_amdgcn_mfma_f32_16x16x32_bf16(ak, bq[ds], a, 0, 0, 0);
            }
            accs[kb] = a;
        }

        // ---- mask + scale + in-lane online softmax (16 keys/lane, q=l15) ----
        float s[16];
        float tmax = -1e30f;
        #pragma unroll
        for (int kb = 0; kb < 4; ++kb) {
            f32x4 mk = *(const f32x4*)&maskf[kt + kb * 16 + l4 * 4];
            #pragma unroll
            for (int jj = 0; jj < 4; ++jj) {
                float val = fmaf(accs[kb][jj], SC, mk[jj]);
                s[kb * 4 + jj] = val;
                tmax = fmaxf(tmax, val);
            }
        }
        tmax = fmaxf(tmax, __shfl_xor(tmax, 16));
        tmax = fmaxf(tmax, __shfl_xor(tmax, 32));

        if (__any(tmax > m_run + 8.0f)) {   // defer-max (T13)
            float mnew = fmaxf(m_run, tmax);
            float r = __builtin_amdgcn_exp2f(m_run - mnew);
            l_run *= r;
            #pragma unroll
            for (int db = 0; db < 4; ++db)
                #pragma unroll
                for (int jj = 0; jj < 4; ++jj) acc_o[db][jj] *= r;
            m_run = mnew;
        }

        float psum = 0.0f;
        unsigned w[8];
        #pragma unroll
        for (int kb = 0; kb < 4; ++kb) {
            float p0 = __builtin_amdgcn_exp2f(s[kb * 4 + 0] - m_run);
            float p1 = __builtin_amdgcn_exp2f(s[kb * 4 + 1] - m_run);
            float p2 = __builtin_amdgcn_exp2f(s[kb * 4 + 2] - m_run);
            float p3 = __builtin_amdgcn_exp2f(s[kb * 4 + 3] - m_run);
            psum += (p0 + p1) + (p2 + p3);
            w[kb * 2]     = pkbf(p0, p1);
            w[kb * 2 + 1] = pkbf(p2, p3);
        }
        psum += __shfl_xor(psum, 16);
        psum += __shfl_xor(psum, 32);
        l_run += psum;

        // ---- PV: O[q][d] += P x V ; P redistributed across l4-groups via shfl ----
        #pragma unroll
        for (int ks = 0; ks < 2; ++ks) {
            unsigned a0s = __shfl(w[4 * ks + 0], srcA);
            unsigned a1s = __shfl(w[4 * ks + 1], srcA);
            unsigned a2s = __shfl(w[4 * ks + 2], srcA);
            unsigned a3s = __shfl(w[4 * ks + 3], srcA);
            unsigned b0s = __shfl(w[4 * ks + 0], srcB);
            unsigned b1s = __shfl(w[4 * ks + 1], srcB);
            unsigned b2s = __shfl(w[4 * ks + 2], srcB);
            unsigned b3s = __shfl(w[4 * ks + 3], srcB);
            u32x4 ua = (u32x4){h2 ? a2s : a0s, h2 ? a3s : a1s,
                               h2 ? b2s : b0s, h2 ? b3s : b1s};
            bf16x8 pa = *(bf16x8*)&ua;
            #pragma unroll
            for (int db = 0; db < 4; ++db) {
                const int row = db * 16 + l15;
                bf16x8 bv = *(const bf16x8*)&Vl[cur][row * 64 + ((ks * 32 + l4 * 8) ^ ((row & 7) << 3))];
                acc_o[db] = __builtin_amdgcn_mfma_f32_16x16x32_bf16(pa, bv, acc_o[db], 0, 0, 0);
            }
        }

        if (t < 15) {   // write next tile into alternate buffer
            *(u32x2*)&Kl[cur ^ 1][kwr] = (u32x2){pkbf(kreg[0], kreg[1]), pkbf(kreg[2], kreg[3])};
            *(u32x2*)&Vl[cur ^ 1][vwr] = (u32x2){pkbf(vv[0], vv[1]), pkbf(vv[2], vv[3])};
        }
        cur ^= 1;
    }

    // ---- channel gate: gate[q][e] = A(am: m=q) x B(W^T: n=e), same C layout as O ----
    f32x4 acc_g[4];
    #pragma unroll
    for (int i = 0; i < 4; ++i) acc_g[i] = (f32x4){0.f, 0.f, 0.f, 0.f};

    bf16x8 bam[2];
    #pragma unroll
    for (int ds = 0; ds < 2; ++ds) {
        const f32x4* p1 = (const f32x4*)(V1p + (size_t)qrow * D + ds * 32 + l4 * 8);
        const f32x4* pk = (const f32x4*)(Kp  + (size_t)qrow * D + ds * 32 + l4 * 8);
        f32x4 a0 = p1[0], a1 = p1[1], c0 = pk[0], c1 = pk[1];
        u32x4 u = (u32x4){pkbf(a0[0]*c0[0], a0[1]*c0[1]), pkbf(a0[2]*c0[2], a0[3]*c0[3]),
                          pkbf(a1[0]*c1[0], a1[1]*c1[1]), pkbf(a1[2]*c1[2], a1[3]*c1[3])};
        bam[ds] = *(bf16x8*)&u;
    }
    #pragma unroll
    for (int eb = 0; eb < 4; ++eb) {
        #pragma unroll
        for (int ds = 0; ds < 2; ++ds) {
            const f32x4* pw = (const f32x4*)(W + (size_t)(eb * 16 + l15) * D + ds * 32 + l4 * 8);
            f32x4 x0 = pw[0], x1 = pw[1];
            u32x4 u = (u32x4){pkbf(x0[0], x0[1]), pkbf(x0[2], x0[3]),
                              pkbf(x1[0], x1[1]), pkbf(x1[2], x1[3])};
            bf16x8 bw = *(bf16x8*)&u;
            acc_g[eb] = __builtin_amdgcn_mfma_f32_16x16x32_bf16(bam[ds], bw, acc_g[eb], 0, 0, 0);
        }
    }

    // ---- epilogue: out[q][d] = (O/l) * sigmoid(gate + b) ----
    float inv = 1.0f / l_run;           // valid for q = l15
    float invr[4];
    #pragma unroll
    for (int r = 0; r < 4; ++r) invr[r] = __shfl(inv, l4 * 4 + r);   // q = l4*4+r

    #pragma unroll
    for (int db = 0; db < 4; ++db) {
        const float bc = bch[db * 16 + l15];
        #pragma unroll
        for (int r = 0; r < 4; ++r) {
            const int ql = l4 * 4 + r;                  // C row -> q_local
            float o = acc_o[db][r] * invr[r];
            float z = acc_g[db][r] + bc;
            float gate = 1.0f / (1.0f + __expf(-z));
            out_attn[base + (size_t)(q0 + ql) * D + db * 16 + l15] = o * gate;
        }
    }
}

extern "C" void kernel_launch(void* const* d_in, const int* in_sizes, int n_in,
                              void* d_out, int out_size, void* d_ws, size_t ws_size,
                              hipStream_t stream) {
    const float* gv   = (const float*)d_in[0];
    const float* q2   = (const float*)d_in[1];
    const float* keyp = (const float*)d_in[2];
    const int*   mask = (const int*)  d_in[3];
    const float* v1   = (const float*)d_in[4];
    const float* v2   = (const float*)d_in[5];
    const float* W    = (const float*)d_in[6];
    const float* bch  = (const float*)d_in[7];
    float* out = (float*)d_out;

    dim3 grid(64, 4);   // (b*h, 256-row q-tile) = 256 blocks = 1/CU, 16 waves/CU
    aoa_attn_kernel<<<grid, 1024, 0, stream>>>(gv, q2, keyp, mask, v1, v2, W, bch, out);
}

// Round 13
// 41.390 us; speedup vs baseline: 2.3236x; 1.2785x over previous
//
#include <hip/hip_runtime.h>
#include <hip/hip_bf16.h>

typedef __attribute__((ext_vector_type(4)))  float f32x4;
typedef __attribute__((ext_vector_type(16))) float f32x16;
typedef __attribute__((ext_vector_type(8)))  short bf16x8;
typedef __attribute__((ext_vector_type(4)))  unsigned u32x4;
typedef __attribute__((ext_vector_type(2)))  unsigned u32x2;

#define NEG_INF_F (-1000000000.0f)

// native bf16 RNE converts -> compiler emits v_cvt_pk_bf16_f32
__device__ inline unsigned pkbf(float a, float b) {
    union { __hip_bfloat16 h; unsigned short u; } x, y;
    x.h = __float2bfloat16(a);
    y.h = __float2bfloat16(b);
    return (unsigned)x.u | ((unsigned)y.u << 16);
}

// ---------- prep: per-b compaction of valid (mask!=0) key indices ----------
// grid 8 (one per b), 1024 thr. vidx[b][pos<nv] = key id; pad [nv,1024)=0.
// padmask[b][pos] = 0 if pos<nv else NEG_INF. nvalid[b] = nv.
__global__ __launch_bounds__(1024) void aoa_prep_kernel(
    const int* __restrict__ maskp,
    int* __restrict__ vidx, float* __restrict__ padmask, int* __restrict__ nvalid)
{
    const int b   = blockIdx.x;
    const int tid = threadIdx.x;
    const int lane = tid & 63;

    const int m = maskp[b * 1024 + tid] ? 1 : 0;
    unsigned long long bal = __ballot(m);
    const int wpre = __popcll(bal & ((1ull << lane) - 1ull));

    __shared__ int wsum[16], woff[16];
    if (lane == 63) wsum[tid >> 6] = wpre + m;
    __syncthreads();
    if (tid < 16) {
        int off = 0;
        for (int i = 0; i < tid; ++i) off += wsum[i];
        woff[tid] = off;
    }
    __syncthreads();
    const int pos = woff[tid >> 6] + wpre;
    const int nv  = woff[15] + wsum[15];

    if (m) vidx[b * 1024 + pos] = tid;
    if (tid >= nv) vidx[b * 1024 + tid] = 0;     // pad -> any valid row; killed by padmask
    padmask[b * 1024 + tid] = (tid < nv) ? 0.0f : NEG_INF_F;
    if (tid == 0) nvalid[b] = nv;
}

// ---------- attention: R8 structure + gathered keys (NT ~ nv/64 tiles) ----------
// Block = 8 warps x 32 q = 256 q. Grid (64 bh, 4 qt) = 1 block/CU.
// mfma_f32_32x32x16_bf16:
//   A[m][k]: m=lane&31, k=(lane>>5)*8+j ; B[k][n]: n=lane&31, k=(lane>>5)*8+j
//   C[m][n]: n=lane&31, m=crow(r,h)=(r&3)+8*(r>>2)+4*(lane>>5)
// QK^T swapped -> lane holds q, 32 keys in regs; softmax in-lane; P via
// cvt_pk + permlane32_swap; PV B-operand from transposed Vt LDS; dbuf (T14);
// intra-tile half-pipelining (QK h1 before SM h0; SM h1 between PV h0/h1).
__global__ __launch_bounds__(512) void aoa_attn_kernel(
    const float* __restrict__ gv,
    const float* __restrict__ q2,
    const float* __restrict__ keyp,
    const float* __restrict__ v1,
    const float* __restrict__ v2,
    const float* __restrict__ W,
    const float* __restrict__ bch,
    const int*   __restrict__ vidx,
    const float* __restrict__ padmask,
    const int*   __restrict__ nvalid,
    float* __restrict__ out)
{
    constexpr int S = 1024, D = 64;
    const int bh  = blockIdx.x;
    const int qt  = blockIdx.y;
    const int b   = bh >> 3;
    const int tid = threadIdx.x;
    const int wid = tid >> 6;
    const int lane = tid & 63;
    const int l31 = lane & 31;
    const int h   = lane >> 5;

    float* out_attn = out + 512;
    if (bh == 0 && qt == 0) out[tid] = gv[tid];

    __shared__ float pmL[S];               // 0 or NEG_INF (gathered order)
    __shared__ int   vidxL[S];             // gathered key ids
    __shared__ short Klds[2][64][72];      // [buf][key][d], 144B stride
    __shared__ short Vt[2][64][72];        // [buf][d][key]
    __shared__ float Lw[8][32];            // per-warp 1/l per q

    for (int i = tid; i < S; i += 512) {
        pmL[i]   = padmask[b * S + i];
        vidxL[i] = vidx[b * S + i];
    }

    const int nv = nvalid[b];
    const int NT = (nv + 63) >> 6;

    const size_t base = (size_t)bh * S * D;
    const float* Qp  = q2   + base;
    const float* Kp  = keyp + base;
    const float* V1p = v1   + base;
    const float* V2p = v2   + base;

    const int q0   = qt * 256 + wid * 32;
    const int qrow = q0 + l31;

    // Q B-fragments: bq[ds][j] = Q[qrow][ds*16 + h*8 + j]
    bf16x8 bq[4];
    #pragma unroll
    for (int ds = 0; ds < 4; ++ds) {
        const f32x4* p = (const f32x4*)(Qp + (size_t)qrow * D + ds * 16 + h * 8);
        f32x4 x0 = p[0], x1 = p[1];
        u32x4 u = (u32x4){pkbf(x0[0], x0[1]), pkbf(x0[2], x0[3]),
                          pkbf(x1[0], x1[1]), pkbf(x1[2], x1[3])};
        bq[ds] = *(bf16x8*)&u;
    }

    f32x16 acc_o[2];
    #pragma unroll
    for (int dh = 0; dh < 2; ++dh)
        #pragma unroll
        for (int r = 0; r < 16; ++r) acc_o[dh][r] = 0.0f;

    float m_run = -1e30f, l_run = 0.0f;
    const float SC = 0.125f * 1.4426950408889634f;   // D^-0.5 * log2(e)

    // staging indices (512 threads)
    const int kk   = tid >> 3;          // K row 0..63
    const int d0   = (tid & 7) << 3;    // K d-offset
    const int dcol = tid & 63;          // Vt d-column
    const int kr0  = (tid >> 6) << 3;   // Vt key chunk = wid*8

    __syncthreads();                    // vidxL/pmL ready

    // prologue: tile 0 (gathered) -> regs -> buf 0
    f32x4 kA, kB;
    float vv[8];
    {
        const f32x4* src = (const f32x4*)(Kp + (size_t)vidxL[kk] * D + d0);
        kA = src[0]; kB = src[1];
        #pragma unroll
        for (int i = 0; i < 8; ++i) vv[i] = V2p[(size_t)vidxL[kr0 + i] * D + dcol];
    }
    *(u32x4*)&Klds[0][kk][d0] = (u32x4){pkbf(kA[0], kA[1]), pkbf(kA[2], kA[3]),
                                        pkbf(kB[0], kB[1]), pkbf(kB[2], kB[3])};
    *(u32x4*)&Vt[0][dcol][kr0] = (u32x4){pkbf(vv[0], vv[1]), pkbf(vv[2], vv[3]),
                                         pkbf(vv[4], vv[5]), pkbf(vv[6], vv[7])};
    int cur = 0;

    for (int t = 0; t < NT; ++t) {
        const int kt = t * 64;
        __syncthreads();   // buf[cur] visible; buf[cur^1] free

        if (t < NT - 1) {   // issue next tile's loads; land under compute
            const f32x4* src = (const f32x4*)(Kp + (size_t)vidxL[kt + 64 + kk] * D + d0);
            kA = src[0]; kB = src[1];
            #pragma unroll
            for (int i = 0; i < 8; ++i) vv[i] = V2p[(size_t)vidxL[kt + 64 + kr0 + i] * D + dcol];
        }

        // ---- QK^T half 0 (gathered keys kt+0..31) ----
        f32x16 a0;
        #pragma unroll
        for (int r = 0; r < 16; ++r) a0[r] = 0.0f;
        #pragma unroll
        for (int ds = 0; ds < 4; ++ds) {
            bf16x8 ak = *(const bf16x8*)&Klds[cur][l31][ds * 16 + h * 8];
            a0 = __builtin_amdgcn_mfma_f32_32x32x16_bf16(ak, bq[ds], a0, 0, 0, 0);
        }
        // ---- QK^T half 1 — issued BEFORE softmax(h0) ----
        f32x16 a1;
        #pragma unroll
        for (int r = 0; r < 16; ++r) a1[r] = 0.0f;
        #pragma unroll
        for (int ds = 0; ds < 4; ++ds) {
            bf16x8 ak = *(const bf16x8*)&Klds[cur][32 + l31][ds * 16 + h * 8];
            a1 = __builtin_amdgcn_mfma_f32_32x32x16_bf16(ak, bq[ds], a1, 0, 0, 0);
        }

        // ---- softmax half 0 (VALU; overlaps QK h1) ----
        unsigned w0[8];
        {
            float s[16], tmax = -1e30f;
            #pragma unroll
            for (int g = 0; g < 4; ++g) {
                f32x4 mk = *(const f32x4*)&pmL[kt + g * 8 + h * 4];
                #pragma unroll
                for (int j = 0; j < 4; ++j) {
                    float val = fmaf(a0[g * 4 + j], SC, mk[j]);
                    s[g * 4 + j] = val;
                    tmax = fmaxf(tmax, val);
                }
            }
            tmax = fmaxf(tmax, __shfl_xor(tmax, 32));
            if (__any(tmax > m_run + 8.0f)) {   // defer-max (T13)
                float mnew = fmaxf(m_run, tmax);
                float r = __builtin_amdgcn_exp2f(m_run - mnew);
                l_run *= r;
                #pragma unroll
                for (int dh = 0; dh < 2; ++dh)
                    #pragma unroll
                    for (int r2 = 0; r2 < 16; ++r2) acc_o[dh][r2] *= r;
                m_run = mnew;
            }
            float ps0 = 0.f, ps1 = 0.f;
            #pragma unroll
            for (int i = 0; i < 8; ++i) {
                float p0 = __builtin_amdgcn_exp2f(s[2 * i]     - m_run);
                float p1 = __builtin_amdgcn_exp2f(s[2 * i + 1] - m_run);
                ps0 += p0; ps1 += p1;
                w0[i] = pkbf(p0, p1);
            }
            float psum = ps0 + ps1;
            psum += __shfl_xor(psum, 32);
            l_run += psum;
        }

        // ---- PV half 0 ----
        #pragma unroll
        for (int t2 = 0; t2 < 2; ++t2) {
            u32x2 r0 = __builtin_amdgcn_permlane32_swap(w0[t2 * 4 + 0], w0[t2 * 4 + 2], false, false);
            u32x2 r1 = __builtin_amdgcn_permlane32_swap(w0[t2 * 4 + 1], w0[t2 * 4 + 3], false, false);
            u32x4 ua = (u32x4){r0[0], r1[0], r0[1], r1[1]};
            bf16x8 pa = *(bf16x8*)&ua;
            #pragma unroll
            for (int dh = 0; dh < 2; ++dh) {
                bf16x8 bv = *(const bf16x8*)&Vt[cur][dh * 32 + l31][t2 * 16 + h * 8];
                acc_o[dh] = __builtin_amdgcn_mfma_f32_32x32x16_bf16(pa, bv, acc_o[dh], 0, 0, 0);
            }
        }

        // ---- softmax half 1 (VALU; overlaps PV h0) ----
        unsigned w1[8];
        {
            float s[16], tmax = -1e30f;
            #pragma unroll
            for (int g = 0; g < 4; ++g) {
                f32x4 mk = *(const f32x4*)&pmL[kt + 32 + g * 8 + h * 4];
                #pragma unroll
                for (int j = 0; j < 4; ++j) {
                    float val = fmaf(a1[g * 4 + j], SC, mk[j]);
                    s[g * 4 + j] = val;
                    tmax = fmaxf(tmax, val);
                }
            }
            tmax = fmaxf(tmax, __shfl_xor(tmax, 32));
            if (__any(tmax > m_run + 8.0f)) {
                float mnew = fmaxf(m_run, tmax);
                float r = __builtin_amdgcn_exp2f(m_run - mnew);
                l_run *= r;
                #pragma unroll
                for (int dh = 0; dh < 2; ++dh)
                    #pragma unroll
                    for (int r2 = 0; r2 < 16; ++r2) acc_o[dh][r2] *= r;
                m_run = mnew;
            }
            float ps0 = 0.f, ps1 = 0.f;
            #pragma unroll
            for (int i = 0; i < 8; ++i) {
                float p0 = __builtin_amdgcn_exp2f(s[2 * i]     - m_run);
                float p1 = __builtin_amdgcn_exp2f(s[2 * i + 1] - m_run);
                ps0 += p0; ps1 += p1;
                w1[i] = pkbf(p0, p1);
            }
            float psum = ps0 + ps1;
            psum += __shfl_xor(psum, 32);
            l_run += psum;
        }

        // ---- PV half 1 ----
        #pragma unroll
        for (int t2 = 0; t2 < 2; ++t2) {
            u32x2 r0 = __builtin_amdgcn_permlane32_swap(w1[t2 * 4 + 0], w1[t2 * 4 + 2], false, false);
            u32x2 r1 = __builtin_amdgcn_permlane32_swap(w1[t2 * 4 + 1], w1[t2 * 4 + 3], false, false);
            u32x4 ua = (u32x4){r0[0], r1[0], r0[1], r1[1]};
            bf16x8 pa = *(bf16x8*)&ua;
            #pragma unroll
            for (int dh = 0; dh < 2; ++dh) {
                bf16x8 bv = *(const bf16x8*)&Vt[cur][dh * 32 + l31][32 + t2 * 16 + h * 8];
                acc_o[dh] = __builtin_amdgcn_mfma_f32_32x32x16_bf16(pa, bv, acc_o[dh], 0, 0, 0);
            }
        }

        if (t < NT - 1) {   // write next tile into alternate buffer
            *(u32x4*)&Klds[cur ^ 1][kk][d0] = (u32x4){pkbf(kA[0], kA[1]), pkbf(kA[2], kA[3]),
                                                      pkbf(kB[0], kB[1]), pkbf(kB[2], kB[3])};
            *(u32x4*)&Vt[cur ^ 1][dcol][kr0] = (u32x4){pkbf(vv[0], vv[1]), pkbf(vv[2], vv[3]),
                                                       pkbf(vv[4], vv[5]), pkbf(vv[6], vv[7])};
        }
        cur ^= 1;
    }

    // ---- channel gate: gate[q][e] = sum_d am[q][d]*W[e][d], same C layout as O ----
    f32x16 acc_g[2];
    #pragma unroll
    for (int eh = 0; eh < 2; ++eh)
        #pragma unroll
        for (int r = 0; r < 16; ++r) acc_g[eh][r] = 0.0f;

    bf16x8 bam[4];
    #pragma unroll
    for (int ds = 0; ds < 4; ++ds) {
        const f32x4* p1 = (const f32x4*)(V1p + (size_t)qrow * D + ds * 16 + h * 8);
        const f32x4* pk = (const f32x4*)(Kp  + (size_t)qrow * D + ds * 16 + h * 8);
        f32x4 a0 = p1[0], a1 = p1[1], c0 = pk[0], c1 = pk[1];
        u32x4 u = (u32x4){pkbf(a0[0]*c0[0], a0[1]*c0[1]), pkbf(a0[2]*c0[2], a0[3]*c0[3]),
                          pkbf(a1[0]*c1[0], a1[1]*c1[1]), pkbf(a1[2]*c1[2], a1[3]*c1[3])};
        bam[ds] = *(bf16x8*)&u;
    }
    #pragma unroll
    for (int eh = 0; eh < 2; ++eh) {
        #pragma unroll
        for (int ds = 0; ds < 4; ++ds) {
            const f32x4* pw = (const f32x4*)(W + (size_t)(eh * 32 + l31) * D + ds * 16 + h * 8);
            f32x4 x0 = pw[0], x1 = pw[1];
            u32x4 u = (u32x4){pkbf(x0[0], x0[1]), pkbf(x0[2], x0[3]),
                              pkbf(x1[0], x1[1]), pkbf(x1[2], x1[3])};
            bf16x8 bw = *(bf16x8*)&u;
            acc_g[eh] = __builtin_amdgcn_mfma_f32_32x32x16_bf16(bam[ds], bw, acc_g[eh], 0, 0, 0);
        }
    }

    // ---- epilogue: out = (O/l) * sigmoid(gate + b) ----
    Lw[wid][l31] = 1.0f / l_run;
    __builtin_amdgcn_wave_barrier();
    const float bv0 = bch[l31], bv1 = bch[32 + l31];
    #pragma unroll
    for (int dh = 0; dh < 2; ++dh) {
        const float bc = dh ? bv1 : bv0;
        #pragma unroll
        for (int r = 0; r < 16; ++r) {
            const int ql = (r & 3) + 8 * (r >> 2) + 4 * h;   // crow(r,h)
            float invl = Lw[wid][ql];
            float o = acc_o[dh][r] * invl;
            float z = acc_g[dh][r] + bc;
            float gate = 1.0f / (1.0f + __expf(-z));
            out_attn[base + (size_t)(q0 + ql) * D + dh * 32 + l31] = o * gate;
        }
    }
}

extern "C" void kernel_launch(void* const* d_in, const int* in_sizes, int n_in,
                              void* d_out, int out_size, void* d_ws, size_t ws_size,
                              hipStream_t stream) {
    const float* gv   = (const float*)d_in[0];
    const float* q2   = (const float*)d_in[1];
    const float* keyp = (const float*)d_in[2];
    const int*   mask = (const int*)  d_in[3];
    const float* v1   = (const float*)d_in[4];
    const float* v2   = (const float*)d_in[5];
    const float* W    = (const float*)d_in[6];
    const float* bch  = (const float*)d_in[7];
    float* out = (float*)d_out;

    int*   vidx    = (int*)d_ws;                   // 8*1024 int
    float* padmask = (float*)(vidx + 8 * 1024);    // 8*1024 f32
    int*   nvalid  = (int*)(padmask + 8 * 1024);   // 8 int   (total ~65.6 KB)

    aoa_prep_kernel<<<8, 1024, 0, stream>>>(mask, vidx, padmask, nvalid);

    dim3 grid(64, 4);   // (b*h, 256-row q-tile) = 256 blocks = 1/CU
    aoa_attn_kernel<<<grid, 512, 0, stream>>>(gv, q2, keyp, v1, v2, W, bch,
                                              vidx, padmask, nvalid, out);
}